// Round 1
// baseline (807.200 us; speedup 1.0000x reference)
//
#include <hip/hip_runtime.h>
#include <stdint.h>

// Problem constants
#define B_SZ 2048
#define S_SZ 50
#define D_SZ 128
#define T_SZ 32000
#define K4D 512   // folded K = 4*128

typedef __attribute__((ext_vector_type(8))) short short8v;   // 8 bf16 (4 VGPR) MFMA A/B frag
typedef __attribute__((ext_vector_type(4))) float floatx4;   // MFMA C/D frag

__device__ __forceinline__ unsigned short f2bf(float f) {
  uint32_t u = __float_as_uint(f);
  uint32_t r = (u + 0x7fffu + ((u >> 16) & 1u)) >> 16;
  return (unsigned short)r;
}

// ---------------- kernel 1: mean over S ----------------
// one wave per batch row; float2 per lane => 512B/wave coalesced loads
__global__ __launch_bounds__(256) void k_mean(const float* __restrict__ enc,
                                              float* __restrict__ data) {
  int wid = threadIdx.x >> 6;
  int lane = threadIdx.x & 63;
  int b = blockIdx.x * 4 + wid;
  const float* src = enc + (size_t)b * (S_SZ * D_SZ) + lane * 2;
  float s0 = 0.f, s1 = 0.f;
#pragma unroll
  for (int s = 0; s < S_SZ; ++s) {
    float2 v = *(const float2*)(src + s * D_SZ);
    s0 += v.x; s1 += v.y;
  }
  float2 o; o.x = s0 * (1.f / 50.f); o.y = s1 * (1.f / 50.f);
  *(float2*)(data + (size_t)b * D_SZ + lane * 2) = o;
}

// ---------------- kernel 2: cast + interleave W1..W4 -> W4bf [32000][512] bf16 ----------------
__global__ __launch_bounds__(256) void k_cast(const float* __restrict__ W1, const float* __restrict__ W2,
                                              const float* __restrict__ W3, const float* __restrict__ W4,
                                              unsigned short* __restrict__ w4) {
  int c = blockIdx.x * 256 + threadIdx.x;       // 0 .. 2,048,000
  int e = c * 8;
  int t = e >> 9;
  int col = e & 511;
  int i = col >> 7;
  int d = col & 127;
  const float* src = (i == 0) ? W1 : (i == 1) ? W2 : (i == 2) ? W3 : W4;
  src += (size_t)t * 128 + d;
  float4 a = *(const float4*)src;
  float4 b = *(const float4*)(src + 4);
  union { short8v v; unsigned short u[8]; } pk;
  pk.u[0] = f2bf(a.x); pk.u[1] = f2bf(a.y); pk.u[2] = f2bf(a.z); pk.u[3] = f2bf(a.w);
  pk.u[4] = f2bf(b.x); pk.u[5] = f2bf(b.y); pk.u[6] = f2bf(b.z); pk.u[7] = f2bf(b.w);
  *(short8v*)(w4 + (size_t)t * 512 + col) = pk.v;
}

// ---------------- kernel 3: Gram matrices G_i = W_i^T W_i  (4 x 128 x 128 f32) ----------------
// split-K: 4 mats x 50 chunks of 640 t-rows; LDS holds transposed tile WT[d][t] (pitch 72)
// so BOTH MFMA operands are contiguous row reads (G = WT * WT^T).
__global__ __launch_bounds__(256) void k_gram(const unsigned short* __restrict__ w4,
                                              float* __restrict__ G) {
  __shared__ unsigned short WT[128 * 72];
  int tid = threadIdx.x;
  int lane = tid & 63, wid = tid >> 6;
  int mat = blockIdx.x / 50;
  int chunk = blockIdx.x % 50;
  int t0 = chunk * 640;

  floatx4 acc[2][8];
#pragma unroll
  for (int aa = 0; aa < 2; ++aa)
#pragma unroll
    for (int n = 0; n < 8; ++n) acc[aa][n] = (floatx4){0.f, 0.f, 0.f, 0.f};

  for (int ks = 0; ks < 10; ++ks) {
    __syncthreads();
    // stage 64 t-rows (bf16) transposed into WT[d][t]
    const unsigned short* srow = w4 + (size_t)(t0 + ks * 64 + lane) * 512 + mat * 128;
#pragma unroll
    for (int r = 0; r < 4; ++r) {
      int ch = wid + r * 4;                       // 16B chunk within the 256B row slice
      uint4 v = *(const uint4*)(srow + ch * 8);
      int dbase = ch * 8;
      WT[(dbase + 0) * 72 + lane] = (unsigned short)(v.x & 0xffff);
      WT[(dbase + 1) * 72 + lane] = (unsigned short)(v.x >> 16);
      WT[(dbase + 2) * 72 + lane] = (unsigned short)(v.y & 0xffff);
      WT[(dbase + 3) * 72 + lane] = (unsigned short)(v.y >> 16);
      WT[(dbase + 4) * 72 + lane] = (unsigned short)(v.z & 0xffff);
      WT[(dbase + 5) * 72 + lane] = (unsigned short)(v.z >> 16);
      WT[(dbase + 6) * 72 + lane] = (unsigned short)(v.w & 0xffff);
      WT[(dbase + 7) * 72 + lane] = (unsigned short)(v.w >> 16);
    }
    __syncthreads();
#pragma unroll
    for (int kk = 0; kk < 2; ++kk) {
      int kb = kk * 32 + (lane >> 4) * 8;
      short8v af[2], bfr[8];
#pragma unroll
      for (int aa = 0; aa < 2; ++aa) {
        int row = (wid * 2 + aa) * 16 + (lane & 15);
        af[aa] = *(const short8v*)&WT[row * 72 + kb];
      }
#pragma unroll
      for (int n = 0; n < 8; ++n) {
        int row = n * 16 + (lane & 15);
        bfr[n] = *(const short8v*)&WT[row * 72 + kb];
      }
#pragma unroll
      for (int aa = 0; aa < 2; ++aa)
#pragma unroll
        for (int n = 0; n < 8; ++n)
          acc[aa][n] = __builtin_amdgcn_mfma_f32_16x16x32_bf16(af[aa], bfr[n], acc[aa][n], 0, 0, 0);
    }
  }
  int g8 = lane >> 4, lc = lane & 15;
#pragma unroll
  for (int aa = 0; aa < 2; ++aa)
#pragma unroll
    for (int n = 0; n < 8; ++n)
#pragma unroll
      for (int q = 0; q < 4; ++q) {
        int row = (wid * 2 + aa) * 16 + g8 * 4 + q;
        int col = n * 16 + lc;
        unsafeAtomicAdd(&G[mat * 16384 + row * 128 + col], acc[aa][n][q]);
      }
}

// ---------------- kernel 4: sumsq via quadratic form + build folded data4 (bf16) ----------------
__global__ __launch_bounds__(256) void k_norm(const float* __restrict__ data, const float* __restrict__ G,
                                              const float* __restrict__ pa, const float* __restrict__ pb,
                                              const float* __restrict__ pc, const float* __restrict__ pd,
                                              unsigned short* __restrict__ data4) {
  __shared__ float dsh[16][132];
  __shared__ float Gch[32][132];
  __shared__ float sc[16][4];
  int tid = threadIdx.x;
  int b0 = blockIdx.x * 16;

  { // load 16 data rows
    int e = tid * 8;
    int rr = e >> 7, cc = e & 127;
    float4 v0 = *(const float4*)(data + (size_t)(b0 + rr) * 128 + cc);
    float4 v1 = *(const float4*)(data + (size_t)(b0 + rr) * 128 + cc + 4);
    *(float4*)&dsh[rr][cc] = v0;
    *(float4*)&dsh[rr][cc + 4] = v1;
  }
  int bl = tid >> 4, sub = tid & 15;
  float ss[4];
#pragma unroll
  for (int i = 0; i < 4; ++i) ss[i] = 0.f;

#pragma unroll
  for (int i = 0; i < 4; ++i) {
    for (int jc = 0; jc < 4; ++jc) {
      __syncthreads();
      { // stage 32 rows of G_i
        int e = tid * 16;
        int rr = e >> 7, cc = e & 127;
        const float* gsrc = G + i * 16384 + (jc * 32 + rr) * 128 + cc;
#pragma unroll
        for (int q = 0; q < 4; ++q)
          *(float4*)&Gch[rr][cc + q * 4] = *(const float4*)(gsrc + q * 4);
      }
      __syncthreads();
#pragma unroll
      for (int j2 = 0; j2 < 2; ++j2) {
        int jl = sub + j2 * 16;
        float tmp = 0.f;
#pragma unroll 8
        for (int k4 = 0; k4 < 32; ++k4) {
          float4 g = *(const float4*)&Gch[jl][k4 * 4];
          float4 dd = *(const float4*)&dsh[bl][k4 * 4];
          tmp += g.x * dd.x + g.y * dd.y + g.z * dd.z + g.w * dd.w;
        }
        ss[i] += dsh[bl][jc * 32 + jl] * tmp;
      }
    }
  }
#pragma unroll
  for (int i = 0; i < 4; ++i) {
    ss[i] += __shfl_xor(ss[i], 1);
    ss[i] += __shfl_xor(ss[i], 2);
    ss[i] += __shfl_xor(ss[i], 4);
    ss[i] += __shfl_xor(ss[i], 8);
  }
  if (sub == 0) {
    float cf0 = pa[0], cf1 = pb[0], cf2 = pc[0], cf3 = pd[0];
    sc[bl][0] = cf0 / fmaxf(sqrtf(ss[0]), 1e-5f);
    sc[bl][1] = cf1 / fmaxf(sqrtf(ss[1]), 1e-5f);
    sc[bl][2] = cf2 / fmaxf(sqrtf(ss[2]), 1e-5f);
    sc[bl][3] = cf3 / fmaxf(sqrtf(ss[3]), 1e-5f);
  }
  __syncthreads();
  for (int e = tid; e < 16 * 512; e += 256) {
    int r = e >> 9, col = e & 511;
    int i = col >> 7, d = col & 127;
    float v = dsh[r][d] * sc[r][i];
    data4[(size_t)(b0 + r) * 512 + col] = f2bf(v);
  }
}

// ---------------- kernel 5: main GEMM (2048 x 32000, K=512 bf16) + tanh + target=1.0 ----------------
__global__ __launch_bounds__(256, 2) void k_gemm(const unsigned short* __restrict__ data4,
                                                 const unsigned short* __restrict__ w4,
                                                 float* __restrict__ out, float* __restrict__ target) {
  __shared__ unsigned short As[128 * 64];
  __shared__ unsigned short Bs[128 * 64];
  int tid = threadIdx.x, lane = tid & 63, wid = tid >> 6;
  // bijective XCD-chunked swizzle (4000 % 8 == 0); tm fastest so co-XCD blocks share B panel
  int bid = blockIdx.x;
  int sb = (bid & 7) * 500 + (bid >> 3);
  int tn = sb / 16, tm = sb % 16;
  int m0 = tm * 128, n0 = tn * 128;
  int srow = lane >> 3, slot = lane & 7;
  int wrr = (wid >> 1) * 64, wcc = (wid & 1) * 64;

  floatx4 acc[4][4];
#pragma unroll
  for (int m = 0; m < 4; ++m)
#pragma unroll
    for (int n = 0; n < 4; ++n) acc[m][n] = (floatx4){0.f, 0.f, 0.f, 0.f};

  const char* Abase = (const char*)data4;
  const char* Bbase = (const char*)w4;

  for (int kt = 0; kt < 8; ++kt) {
    if (kt) __syncthreads();
    // stage A/B tiles: linear LDS dest, XOR-swizzled (st-style) global source
#pragma unroll
    for (int u = 0; u < 4; ++u) {
      int row = wid * 32 + u * 8 + srow;
      int sw = ((slot ^ (row & 7)) * 16);
      const char* ga = Abase + (size_t)(m0 + row) * 1024 + kt * 128 + sw;
      const char* gb = Bbase + (size_t)(n0 + row) * 1024 + kt * 128 + sw;
      int lbo = __builtin_amdgcn_readfirstlane(wid * 4096 + u * 1024);
      __builtin_amdgcn_global_load_lds((const __attribute__((address_space(1))) void*)ga,
                                       (__attribute__((address_space(3))) void*)((char*)As + lbo), 16, 0, 0);
      __builtin_amdgcn_global_load_lds((const __attribute__((address_space(1))) void*)gb,
                                       (__attribute__((address_space(3))) void*)((char*)Bs + lbo), 16, 0, 0);
    }
    __syncthreads();
    int g8 = lane >> 4;
#pragma unroll
    for (int kk = 0; kk < 2; ++kk) {
      short8v af[4], bfr[4];
#pragma unroll
      for (int m = 0; m < 4; ++m) {
        int r = wrr + m * 16 + (lane & 15);
        int byteoff = r * 128 + (((kk * 4 + g8) ^ (r & 7)) * 16);
        af[m] = *(const short8v*)((const char*)As + byteoff);
      }
#pragma unroll
      for (int n = 0; n < 4; ++n) {
        int r = wcc + n * 16 + (lane & 15);
        int byteoff = r * 128 + (((kk * 4 + g8) ^ (r & 7)) * 16);
        bfr[n] = *(const short8v*)((const char*)Bs + byteoff);
      }
#pragma unroll
      for (int m = 0; m < 4; ++m)
#pragma unroll
        for (int n = 0; n < 4; ++n)
          acc[m][n] = __builtin_amdgcn_mfma_f32_16x16x32_bf16(af[m], bfr[n], acc[m][n], 0, 0, 0);
    }
  }
  // epilogue: tanh(out) + target=1.0
  int g8 = lane >> 4, lc = lane & 15;
#pragma unroll
  for (int m = 0; m < 4; ++m)
#pragma unroll
    for (int n = 0; n < 4; ++n)
#pragma unroll
      for (int q = 0; q < 4; ++q) {
        int row = m0 + wrr + m * 16 + g8 * 4 + q;
        int col = n0 + wcc + n * 16 + lc;
        float x = acc[m][n][q];
        float e2 = __expf(2.f * x);
        size_t idx = (size_t)row * 32000 + col;
        out[idx] = (e2 - 1.f) / (e2 + 1.f);
        target[idx] = 1.0f;
      }
}

// ---------------- kernel 6: scatter zeros into target ----------------
__global__ __launch_bounds__(256) void k_scatter(const int* __restrict__ ev, float* __restrict__ target) {
  int g = blockIdx.x * 256 + threadIdx.x;
  if (g >= B_SZ * S_SZ) return;
  int b = g / 50;
  int et = ev[g];
  if (et > 0) target[(size_t)b * 32000 + (et - 1)] = 0.f;
}

extern "C" void kernel_launch(void* const* d_in, const int* in_sizes, int n_in,
                              void* d_out, int out_size, void* d_ws, size_t ws_size,
                              hipStream_t stream) {
  const float* enc = (const float*)d_in[0];
  const int* ev = (const int*)d_in[1];
  // d_in[2] = user_type: unused by the reference
  const float* W1 = (const float*)d_in[3];
  const float* W2 = (const float*)d_in[4];
  const float* W3 = (const float*)d_in[5];
  const float* W4 = (const float*)d_in[6];
  const float* pa = (const float*)d_in[7];
  const float* pb = (const float*)d_in[8];
  const float* pc = (const float*)d_in[9];
  const float* pd = (const float*)d_in[10];

  float* out = (float*)d_out;
  float* target = out + (size_t)B_SZ * T_SZ;

  char* ws = (char*)d_ws;
  float* data = (float*)ws;                                  // 1 MB
  unsigned short* data4 = (unsigned short*)(ws + (1 << 20)); // 2 MB
  float* G = (float*)(ws + 3 * (1 << 20));                   // 256 KB
  unsigned short* w4 = (unsigned short*)(ws + 4 * (1 << 20));// 31.25 MB

  hipMemsetAsync(G, 0, 4 * 128 * 128 * sizeof(float), stream);
  k_mean<<<512, 256, 0, stream>>>(enc, data);
  k_cast<<<8000, 256, 0, stream>>>(W1, W2, W3, W4, w4);
  k_gram<<<200, 256, 0, stream>>>(w4, G);
  k_norm<<<128, 256, 0, stream>>>(data, G, pa, pb, pc, pd, data4);
  k_gemm<<<4000, 256, 0, stream>>>(data4, w4, out, target);
  k_scatter<<<400, 256, 0, stream>>>(ev, target);
}

// Round 2
// 738.359 us; speedup vs baseline: 1.0932x; 1.0932x over previous
//
#include <hip/hip_runtime.h>
#include <stdint.h>

// Problem constants
#define B_SZ 2048
#define S_SZ 50
#define D_SZ 128
#define T_SZ 32000

typedef __attribute__((ext_vector_type(8))) short short8v;   // 8 bf16 (4 VGPR) MFMA A/B frag
typedef __attribute__((ext_vector_type(4))) float floatx4;   // MFMA C/D frag

__device__ __forceinline__ unsigned short f2bf(float f) {
  uint32_t u = __float_as_uint(f);
  uint32_t r = (u + 0x7fffu + ((u >> 16) & 1u)) >> 16;
  return (unsigned short)r;
}

// ---------------- kernel 1: mean over S ----------------
__global__ __launch_bounds__(256) void k_mean(const float* __restrict__ enc,
                                              float* __restrict__ data) {
  int wid = threadIdx.x >> 6;
  int lane = threadIdx.x & 63;
  int b = blockIdx.x * 4 + wid;
  const float* src = enc + (size_t)b * (S_SZ * D_SZ) + lane * 2;
  float s0 = 0.f, s1 = 0.f;
#pragma unroll
  for (int s = 0; s < S_SZ; ++s) {
    float2 v = *(const float2*)(src + s * D_SZ);
    s0 += v.x; s1 += v.y;
  }
  float2 o; o.x = s0 * (1.f / 50.f); o.y = s1 * (1.f / 50.f);
  *(float2*)(data + (size_t)b * D_SZ + lane * 2) = o;
}

// ---------------- kernel 2: cast + interleave W1..W4 -> W4bf [32000][512] bf16 ----------------
__global__ __launch_bounds__(256) void k_cast(const float* __restrict__ W1, const float* __restrict__ W2,
                                              const float* __restrict__ W3, const float* __restrict__ W4,
                                              unsigned short* __restrict__ w4) {
  int c = blockIdx.x * 256 + threadIdx.x;       // 0 .. 2,048,000
  int e = c * 8;
  int t = e >> 9;
  int col = e & 511;
  int i = col >> 7;
  int d = col & 127;
  const float* src = (i == 0) ? W1 : (i == 1) ? W2 : (i == 2) ? W3 : W4;
  src += (size_t)t * 128 + d;
  float4 a = *(const float4*)src;
  float4 b = *(const float4*)(src + 4);
  union { short8v v; unsigned short u[8]; } pk;
  pk.u[0] = f2bf(a.x); pk.u[1] = f2bf(a.y); pk.u[2] = f2bf(a.z); pk.u[3] = f2bf(a.w);
  pk.u[4] = f2bf(b.x); pk.u[5] = f2bf(b.y); pk.u[6] = f2bf(b.z); pk.u[7] = f2bf(b.w);
  *(short8v*)(w4 + (size_t)t * 512 + col) = pk.v;
}

// ---------------- kernel 3: Gram partials Gp[bid] = (W_mat chunk)^T (W_mat chunk) ----------------
// 4 mats x 50 chunks of 640 t-rows; NO atomics — each block owns its 64 KB partial.
__global__ __launch_bounds__(256) void k_gram(const unsigned short* __restrict__ w4,
                                              float* __restrict__ Gp) {
  __shared__ unsigned short WT[128 * 72];
  int tid = threadIdx.x;
  int lane = tid & 63, wid = tid >> 6;
  int mat = blockIdx.x / 50;
  int chunk = blockIdx.x % 50;
  int t0 = chunk * 640;

  floatx4 acc[2][8];
#pragma unroll
  for (int aa = 0; aa < 2; ++aa)
#pragma unroll
    for (int n = 0; n < 8; ++n) acc[aa][n] = (floatx4){0.f, 0.f, 0.f, 0.f};

  for (int ks = 0; ks < 10; ++ks) {
    __syncthreads();
    const unsigned short* srow = w4 + (size_t)(t0 + ks * 64 + lane) * 512 + mat * 128;
#pragma unroll
    for (int r = 0; r < 4; ++r) {
      int ch = wid + r * 4;
      uint4 v = *(const uint4*)(srow + ch * 8);
      int dbase = ch * 8;
      WT[(dbase + 0) * 72 + lane] = (unsigned short)(v.x & 0xffff);
      WT[(dbase + 1) * 72 + lane] = (unsigned short)(v.x >> 16);
      WT[(dbase + 2) * 72 + lane] = (unsigned short)(v.y & 0xffff);
      WT[(dbase + 3) * 72 + lane] = (unsigned short)(v.y >> 16);
      WT[(dbase + 4) * 72 + lane] = (unsigned short)(v.z & 0xffff);
      WT[(dbase + 5) * 72 + lane] = (unsigned short)(v.z >> 16);
      WT[(dbase + 6) * 72 + lane] = (unsigned short)(v.w & 0xffff);
      WT[(dbase + 7) * 72 + lane] = (unsigned short)(v.w >> 16);
    }
    __syncthreads();
#pragma unroll
    for (int kk = 0; kk < 2; ++kk) {
      int kb = kk * 32 + (lane >> 4) * 8;
      short8v af[2], bfr[8];
#pragma unroll
      for (int aa = 0; aa < 2; ++aa) {
        int row = (wid * 2 + aa) * 16 + (lane & 15);
        af[aa] = *(const short8v*)&WT[row * 72 + kb];
      }
#pragma unroll
      for (int n = 0; n < 8; ++n) {
        int row = n * 16 + (lane & 15);
        bfr[n] = *(const short8v*)&WT[row * 72 + kb];
      }
#pragma unroll
      for (int aa = 0; aa < 2; ++aa)
#pragma unroll
        for (int n = 0; n < 8; ++n)
          acc[aa][n] = __builtin_amdgcn_mfma_f32_16x16x32_bf16(af[aa], bfr[n], acc[aa][n], 0, 0, 0);
    }
  }
  float* gp = Gp + (size_t)blockIdx.x * 16384;
  int g8 = lane >> 4, lc = lane & 15;
#pragma unroll
  for (int aa = 0; aa < 2; ++aa)
#pragma unroll
    for (int n = 0; n < 8; ++n)
#pragma unroll
      for (int q = 0; q < 4; ++q) {
        int row = (wid * 2 + aa) * 16 + g8 * 4 + q;
        int col = n * 16 + lc;
        gp[row * 128 + col] = acc[aa][n][q];
      }
}

// ---------------- kernel 3b: reduce Gp -> G (4 x 128 x 128 f32) ----------------
__global__ __launch_bounds__(256) void k_greduce(const float* __restrict__ Gp,
                                                 float* __restrict__ G) {
  int mat = blockIdx.x >> 4;                          // 4 mats x 16 blocks
  int e = ((blockIdx.x & 15) * 256 + threadIdx.x) * 4;
  const float* src = Gp + (size_t)(mat * 50) * 16384 + e;
  float4 s = {0.f, 0.f, 0.f, 0.f};
#pragma unroll 10
  for (int c = 0; c < 50; ++c) {
    float4 v = *(const float4*)(src + (size_t)c * 16384);
    s.x += v.x; s.y += v.y; s.z += v.z; s.w += v.w;
  }
  *(float4*)(G + (size_t)mat * 16384 + e) = s;
}

// ---------------- kernel 4: sumsq via quadratic form + build folded data4 (bf16) ----------------
__global__ __launch_bounds__(256) void k_norm(const float* __restrict__ data, const float* __restrict__ G,
                                              const float* __restrict__ pa, const float* __restrict__ pb,
                                              const float* __restrict__ pc, const float* __restrict__ pd,
                                              unsigned short* __restrict__ data4) {
  __shared__ float dsh[16][132];
  __shared__ float Gch[32][132];
  __shared__ float sc[16][4];
  int tid = threadIdx.x;
  int b0 = blockIdx.x * 16;

  {
    int e = tid * 8;
    int rr = e >> 7, cc = e & 127;
    float4 v0 = *(const float4*)(data + (size_t)(b0 + rr) * 128 + cc);
    float4 v1 = *(const float4*)(data + (size_t)(b0 + rr) * 128 + cc + 4);
    *(float4*)&dsh[rr][cc] = v0;
    *(float4*)&dsh[rr][cc + 4] = v1;
  }
  int bl = tid >> 4, sub = tid & 15;
  float ss[4];
#pragma unroll
  for (int i = 0; i < 4; ++i) ss[i] = 0.f;

#pragma unroll
  for (int i = 0; i < 4; ++i) {
    for (int jc = 0; jc < 4; ++jc) {
      __syncthreads();
      {
        int e = tid * 16;
        int rr = e >> 7, cc = e & 127;
        const float* gsrc = G + i * 16384 + (jc * 32 + rr) * 128 + cc;
#pragma unroll
        for (int q = 0; q < 4; ++q)
          *(float4*)&Gch[rr][cc + q * 4] = *(const float4*)(gsrc + q * 4);
      }
      __syncthreads();
#pragma unroll
      for (int j2 = 0; j2 < 2; ++j2) {
        int jl = sub + j2 * 16;
        float tmp = 0.f;
#pragma unroll 8
        for (int k4 = 0; k4 < 32; ++k4) {
          float4 g = *(const float4*)&Gch[jl][k4 * 4];
          float4 dd = *(const float4*)&dsh[bl][k4 * 4];
          tmp += g.x * dd.x + g.y * dd.y + g.z * dd.z + g.w * dd.w;
        }
        ss[i] += dsh[bl][jc * 32 + jl] * tmp;
      }
    }
  }
#pragma unroll
  for (int i = 0; i < 4; ++i) {
    ss[i] += __shfl_xor(ss[i], 1);
    ss[i] += __shfl_xor(ss[i], 2);
    ss[i] += __shfl_xor(ss[i], 4);
    ss[i] += __shfl_xor(ss[i], 8);
  }
  if (sub == 0) {
    float cf0 = pa[0], cf1 = pb[0], cf2 = pc[0], cf3 = pd[0];
    sc[bl][0] = cf0 / fmaxf(sqrtf(ss[0]), 1e-5f);
    sc[bl][1] = cf1 / fmaxf(sqrtf(ss[1]), 1e-5f);
    sc[bl][2] = cf2 / fmaxf(sqrtf(ss[2]), 1e-5f);
    sc[bl][3] = cf3 / fmaxf(sqrtf(ss[3]), 1e-5f);
  }
  __syncthreads();
  for (int e = tid; e < 16 * 512; e += 256) {
    int r = e >> 9, col = e & 511;
    int i = col >> 7, d = col & 127;
    float v = dsh[r][d] * sc[r][i];
    data4[(size_t)(b0 + r) * 512 + col] = f2bf(v);
  }
}

// ---------------- kernel 5: main GEMM (2048 x 32000, K=512 bf16) + tanh epilogue ----------------
__global__ __launch_bounds__(256, 3) void k_gemm(const unsigned short* __restrict__ data4,
                                                 const unsigned short* __restrict__ w4,
                                                 float* __restrict__ out) {
  __shared__ unsigned short As[128 * 64];
  __shared__ unsigned short Bs[128 * 64];
  int tid = threadIdx.x, lane = tid & 63, wid = tid >> 6;
  // bijective XCD-chunked swizzle (4000 % 8 == 0); tm fastest so co-XCD blocks share B panel
  int bid = blockIdx.x;
  int sb = (bid & 7) * 500 + (bid >> 3);
  int tn = sb / 16, tm = sb % 16;
  int m0 = tm * 128, n0 = tn * 128;
  int srow = lane >> 3, slot = lane & 7;
  int wrr = (wid >> 1) * 64, wcc = (wid & 1) * 64;

  floatx4 acc[4][4];
#pragma unroll
  for (int m = 0; m < 4; ++m)
#pragma unroll
    for (int n = 0; n < 4; ++n) acc[m][n] = (floatx4){0.f, 0.f, 0.f, 0.f};

  const char* Abase = (const char*)data4;
  const char* Bbase = (const char*)w4;

  for (int kt = 0; kt < 8; ++kt) {
    if (kt) __syncthreads();
#pragma unroll
    for (int u = 0; u < 4; ++u) {
      int row = wid * 32 + u * 8 + srow;
      int sw = ((slot ^ (row & 7)) * 16);
      const char* ga = Abase + (size_t)(m0 + row) * 1024 + kt * 128 + sw;
      const char* gb = Bbase + (size_t)(n0 + row) * 1024 + kt * 128 + sw;
      int lbo = __builtin_amdgcn_readfirstlane(wid * 4096 + u * 1024);
      __builtin_amdgcn_global_load_lds((const __attribute__((address_space(1))) void*)ga,
                                       (__attribute__((address_space(3))) void*)((char*)As + lbo), 16, 0, 0);
      __builtin_amdgcn_global_load_lds((const __attribute__((address_space(1))) void*)gb,
                                       (__attribute__((address_space(3))) void*)((char*)Bs + lbo), 16, 0, 0);
    }
    __syncthreads();
    int g8 = lane >> 4;
#pragma unroll
    for (int kk = 0; kk < 2; ++kk) {
      short8v af[4], bfr[4];
#pragma unroll
      for (int m = 0; m < 4; ++m) {
        int r = wrr + m * 16 + (lane & 15);
        int byteoff = r * 128 + (((kk * 4 + g8) ^ (r & 7)) * 16);
        af[m] = *(const short8v*)((const char*)As + byteoff);
      }
#pragma unroll
      for (int n = 0; n < 4; ++n) {
        int r = wcc + n * 16 + (lane & 15);
        int byteoff = r * 128 + (((kk * 4 + g8) ^ (r & 7)) * 16);
        bfr[n] = *(const short8v*)((const char*)Bs + byteoff);
      }
#pragma unroll
      for (int m = 0; m < 4; ++m)
#pragma unroll
        for (int n = 0; n < 4; ++n)
          acc[m][n] = __builtin_amdgcn_mfma_f32_16x16x32_bf16(af[m], bfr[n], acc[m][n], 0, 0, 0);
    }
  }
  // epilogue: tanh -> out only (target handled by k_fill)
  int g8 = lane >> 4, lc = lane & 15;
#pragma unroll
  for (int m = 0; m < 4; ++m)
#pragma unroll
    for (int n = 0; n < 4; ++n)
#pragma unroll
      for (int q = 0; q < 4; ++q) {
        int row = m0 + wrr + m * 16 + g8 * 4 + q;
        int col = n0 + wcc + n * 16 + lc;
        float x = acc[m][n][q];
        float e2 = __expf(2.f * x);
        out[(size_t)row * 32000 + col] = (e2 - 1.f) / (e2 + 1.f);
      }
}

// ---------------- kernel 6: target fill (1.0f) + fused event scatter ----------------
__global__ __launch_bounds__(256) void k_fill(const int* __restrict__ ev,
                                              float* __restrict__ target) {
  int b = blockIdx.x;
  float4* row4 = (float4*)(target + (size_t)b * 32000);
  float4 one = {1.f, 1.f, 1.f, 1.f};
#pragma unroll 4
  for (int j = threadIdx.x; j < 8000; j += 256) row4[j] = one;
  __syncthreads();   // order zero-writes after fills (workgroup-scope fence)
  if (threadIdx.x < 50) {
    int et = ev[b * 50 + threadIdx.x];
    if (et > 0) ((float*)row4)[et - 1] = 0.f;
  }
}

extern "C" void kernel_launch(void* const* d_in, const int* in_sizes, int n_in,
                              void* d_out, int out_size, void* d_ws, size_t ws_size,
                              hipStream_t stream) {
  const float* enc = (const float*)d_in[0];
  const int* ev = (const int*)d_in[1];
  // d_in[2] = user_type: unused by the reference
  const float* W1 = (const float*)d_in[3];
  const float* W2 = (const float*)d_in[4];
  const float* W3 = (const float*)d_in[5];
  const float* W4 = (const float*)d_in[6];
  const float* pa = (const float*)d_in[7];
  const float* pb = (const float*)d_in[8];
  const float* pc = (const float*)d_in[9];
  const float* pd = (const float*)d_in[10];

  float* out = (float*)d_out;
  float* target = out + (size_t)B_SZ * T_SZ;

  char* ws = (char*)d_ws;
  float* data = (float*)ws;                                   // 1 MB @ 0
  unsigned short* data4 = (unsigned short*)(ws + (1 << 20));  // 2 MB @ 1M
  float* G = (float*)(ws + 3 * (1 << 20));                    // 256 KB @ 3M
  unsigned short* w4 = (unsigned short*)(ws + 4 * (1 << 20)); // 31.25 MB @ 4M
  float* Gp = (float*)(ws + 36 * (size_t)(1 << 20));          // 12.8 MB @ 36M

  k_mean<<<512, 256, 0, stream>>>(enc, data);
  k_cast<<<8000, 256, 0, stream>>>(W1, W2, W3, W4, w4);
  k_gram<<<200, 256, 0, stream>>>(w4, Gp);
  k_greduce<<<64, 256, 0, stream>>>(Gp, G);
  k_norm<<<128, 256, 0, stream>>>(data, G, pa, pb, pc, pd, data4);
  k_gemm<<<4000, 256, 0, stream>>>(data4, w4, out);
  k_fill<<<2048, 256, 0, stream>>>(ev, target);
}

// Round 4
// 734.782 us; speedup vs baseline: 1.0986x; 1.0049x over previous
//
#include <hip/hip_runtime.h>
#include <stdint.h>

// Problem constants
#define B_SZ 2048
#define S_SZ 50
#define D_SZ 128
#define T_SZ 32000

typedef __attribute__((ext_vector_type(8))) short short8v;   // 8 bf16 (4 VGPR) MFMA A/B frag
typedef __attribute__((ext_vector_type(4))) float floatx4;   // MFMA C/D frag

__device__ __forceinline__ unsigned short f2bf(float f) {
  uint32_t u = __float_as_uint(f);
  uint32_t r = (u + 0x7fffu + ((u >> 16) & 1u)) >> 16;
  return (unsigned short)r;
}

// ---------------- kernel 2: cast + interleave W1..W4 -> W4bf [32000][512] bf16 ----------------
__global__ __launch_bounds__(256) void k_cast(const float* __restrict__ W1, const float* __restrict__ W2,
                                              const float* __restrict__ W3, const float* __restrict__ W4,
                                              unsigned short* __restrict__ w4) {
  int c = blockIdx.x * 256 + threadIdx.x;       // 0 .. 2,048,000
  int e = c * 8;
  int t = e >> 9;
  int col = e & 511;
  int i = col >> 7;
  int d = col & 127;
  const float* src = (i == 0) ? W1 : (i == 1) ? W2 : (i == 2) ? W3 : W4;
  src += (size_t)t * 128 + d;
  float4 a = *(const float4*)src;
  float4 b = *(const float4*)(src + 4);
  union { short8v v; unsigned short u[8]; } pk;
  pk.u[0] = f2bf(a.x); pk.u[1] = f2bf(a.y); pk.u[2] = f2bf(a.z); pk.u[3] = f2bf(a.w);
  pk.u[4] = f2bf(b.x); pk.u[5] = f2bf(b.y); pk.u[6] = f2bf(b.z); pk.u[7] = f2bf(b.w);
  *(short8v*)(w4 + (size_t)t * 512 + col) = pk.v;
}

// ---------------- kernel 3: Gram partials Gp[bid] = (W_mat chunk)^T (W_mat chunk) ----------------
__global__ __launch_bounds__(256) void k_gram(const unsigned short* __restrict__ w4,
                                              float* __restrict__ Gp) {
  __shared__ unsigned short WT[128 * 72];
  int tid = threadIdx.x;
  int lane = tid & 63, wid = tid >> 6;
  int mat = blockIdx.x / 50;
  int chunk = blockIdx.x % 50;
  int t0 = chunk * 640;

  floatx4 acc[2][8];
#pragma unroll
  for (int aa = 0; aa < 2; ++aa)
#pragma unroll
    for (int n = 0; n < 8; ++n) acc[aa][n] = (floatx4){0.f, 0.f, 0.f, 0.f};

  for (int ks = 0; ks < 10; ++ks) {
    __syncthreads();
    const unsigned short* srow = w4 + (size_t)(t0 + ks * 64 + lane) * 512 + mat * 128;
#pragma unroll
    for (int r = 0; r < 4; ++r) {
      int ch = wid + r * 4;
      uint4 v = *(const uint4*)(srow + ch * 8);
      int dbase = ch * 8;
      WT[(dbase + 0) * 72 + lane] = (unsigned short)(v.x & 0xffff);
      WT[(dbase + 1) * 72 + lane] = (unsigned short)(v.x >> 16);
      WT[(dbase + 2) * 72 + lane] = (unsigned short)(v.y & 0xffff);
      WT[(dbase + 3) * 72 + lane] = (unsigned short)(v.y >> 16);
      WT[(dbase + 4) * 72 + lane] = (unsigned short)(v.z & 0xffff);
      WT[(dbase + 5) * 72 + lane] = (unsigned short)(v.z >> 16);
      WT[(dbase + 6) * 72 + lane] = (unsigned short)(v.w & 0xffff);
      WT[(dbase + 7) * 72 + lane] = (unsigned short)(v.w >> 16);
    }
    __syncthreads();
#pragma unroll
    for (int kk = 0; kk < 2; ++kk) {
      int kb = kk * 32 + (lane >> 4) * 8;
      short8v af[2], bfr[8];
#pragma unroll
      for (int aa = 0; aa < 2; ++aa) {
        int row = (wid * 2 + aa) * 16 + (lane & 15);
        af[aa] = *(const short8v*)&WT[row * 72 + kb];
      }
#pragma unroll
      for (int n = 0; n < 8; ++n) {
        int row = n * 16 + (lane & 15);
        bfr[n] = *(const short8v*)&WT[row * 72 + kb];
      }
#pragma unroll
      for (int aa = 0; aa < 2; ++aa)
#pragma unroll
        for (int n = 0; n < 8; ++n)
          acc[aa][n] = __builtin_amdgcn_mfma_f32_16x16x32_bf16(af[aa], bfr[n], acc[aa][n], 0, 0, 0);
    }
  }
  float* gp = Gp + (size_t)blockIdx.x * 16384;
  int g8 = lane >> 4, lc = lane & 15;
#pragma unroll
  for (int aa = 0; aa < 2; ++aa)
#pragma unroll
    for (int n = 0; n < 8; ++n)
#pragma unroll
      for (int q = 0; q < 4; ++q) {
        int row = (wid * 2 + aa) * 16 + g8 * 4 + q;
        int col = n * 16 + lc;
        gp[row * 128 + col] = acc[aa][n][q];
      }
}

// ---------------- kernel 3b: reduce Gp -> G (4 x 128 x 128 f32) ----------------
__global__ __launch_bounds__(256) void k_greduce(const float* __restrict__ Gp,
                                                 float* __restrict__ G) {
  int mat = blockIdx.x >> 4;
  int e = ((blockIdx.x & 15) * 256 + threadIdx.x) * 4;
  const float* src = Gp + (size_t)(mat * 50) * 16384 + e;
  float4 s = {0.f, 0.f, 0.f, 0.f};
#pragma unroll 10
  for (int c = 0; c < 50; ++c) {
    float4 v = *(const float4*)(src + (size_t)c * 16384);
    s.x += v.x; s.y += v.y; s.z += v.z; s.w += v.w;
  }
  *(float4*)(G + (size_t)mat * 16384 + e) = s;
}

// ---------------- kernel 4: mean(enc) + sumsq via quadratic form + build data4 (bf16) ----------------
__global__ __launch_bounds__(256) void k_norm(const float* __restrict__ enc, const float* __restrict__ G,
                                              const float* __restrict__ pa, const float* __restrict__ pb,
                                              const float* __restrict__ pc, const float* __restrict__ pd,
                                              unsigned short* __restrict__ data4) {
  __shared__ float dsh[16][132];
  __shared__ float Gch[32][132];
  __shared__ float sc[16][4];
  int tid = threadIdx.x;
  int b0 = blockIdx.x * 16;

  { // fused mean over S: thread (r = tid>>4) owns 8 cols
    int r = tid >> 4;
    int c8 = (tid & 15) * 8;
    const float* src = enc + (size_t)(b0 + r) * (S_SZ * D_SZ) + c8;
    float4 s0 = {0.f, 0.f, 0.f, 0.f}, s1 = {0.f, 0.f, 0.f, 0.f};
#pragma unroll 10
    for (int s = 0; s < S_SZ; ++s) {
      float4 v0 = *(const float4*)(src + s * D_SZ);
      float4 v1 = *(const float4*)(src + s * D_SZ + 4);
      s0.x += v0.x; s0.y += v0.y; s0.z += v0.z; s0.w += v0.w;
      s1.x += v1.x; s1.y += v1.y; s1.z += v1.z; s1.w += v1.w;
    }
    const float inv = 1.f / 50.f;
    s0.x *= inv; s0.y *= inv; s0.z *= inv; s0.w *= inv;
    s1.x *= inv; s1.y *= inv; s1.z *= inv; s1.w *= inv;
    *(float4*)&dsh[r][c8] = s0;
    *(float4*)&dsh[r][c8 + 4] = s1;
  }
  int bl = tid >> 4, sub = tid & 15;
  float ss[4];
#pragma unroll
  for (int i = 0; i < 4; ++i) ss[i] = 0.f;

#pragma unroll
  for (int i = 0; i < 4; ++i) {
    for (int jc = 0; jc < 4; ++jc) {
      __syncthreads();
      {
        int e = tid * 16;
        int rr = e >> 7, cc = e & 127;
        const float* gsrc = G + i * 16384 + (jc * 32 + rr) * 128 + cc;
#pragma unroll
        for (int q = 0; q < 4; ++q)
          *(float4*)&Gch[rr][cc + q * 4] = *(const float4*)(gsrc + q * 4);
      }
      __syncthreads();
#pragma unroll
      for (int j2 = 0; j2 < 2; ++j2) {
        int jl = sub + j2 * 16;
        float tmp = 0.f;
#pragma unroll 8
        for (int k4 = 0; k4 < 32; ++k4) {
          float4 g = *(const float4*)&Gch[jl][k4 * 4];
          float4 dd = *(const float4*)&dsh[bl][k4 * 4];
          tmp += g.x * dd.x + g.y * dd.y + g.z * dd.z + g.w * dd.w;
        }
        ss[i] += dsh[bl][jc * 32 + jl] * tmp;
      }
    }
  }
#pragma unroll
  for (int i = 0; i < 4; ++i) {
    ss[i] += __shfl_xor(ss[i], 1);
    ss[i] += __shfl_xor(ss[i], 2);
    ss[i] += __shfl_xor(ss[i], 4);
    ss[i] += __shfl_xor(ss[i], 8);
  }
  if (sub == 0) {
    float cf0 = pa[0], cf1 = pb[0], cf2 = pc[0], cf3 = pd[0];
    sc[bl][0] = cf0 / fmaxf(sqrtf(ss[0]), 1e-5f);
    sc[bl][1] = cf1 / fmaxf(sqrtf(ss[1]), 1e-5f);
    sc[bl][2] = cf2 / fmaxf(sqrtf(ss[2]), 1e-5f);
    sc[bl][3] = cf3 / fmaxf(sqrtf(ss[3]), 1e-5f);
  }
  __syncthreads();
  for (int e = tid; e < 16 * 512; e += 256) {
    int r = e >> 9, col = e & 511;
    int i = col >> 7, d = col & 127;
    float v = dsh[r][d] * sc[r][i];
    data4[(size_t)(b0 + r) * 512 + col] = f2bf(v);
  }
}

// ---------------- kernel 5: main GEMM (2048 x 32000, K=512 bf16), dbuf + counted vmcnt ----------------
__global__ __launch_bounds__(256, 2) void k_gemm(const unsigned short* __restrict__ data4,
                                                 const unsigned short* __restrict__ w4,
                                                 float* __restrict__ out) {
  __shared__ unsigned short As[2][8192];   // 2 x 16 KB
  __shared__ unsigned short Bs[2][8192];   // 2 x 16 KB
  int tid = threadIdx.x, lane = tid & 63, wid = tid >> 6;
  int bid = blockIdx.x;
  int sb = (bid & 7) * 500 + (bid >> 3);   // bijective XCD chunking (4000 % 8 == 0)
  int tn = sb / 16, tm = sb % 16;
  int m0 = tm * 128, n0 = tn * 128;
  int srow = lane >> 3, slot = lane & 7;
  int wrr = (wid >> 1) * 64, wcc = (wid & 1) * 64;

  floatx4 acc[4][4];
#pragma unroll
  for (int m = 0; m < 4; ++m)
#pragma unroll
    for (int n = 0; n < 4; ++n) acc[m][n] = (floatx4){0.f, 0.f, 0.f, 0.f};

  const char* Abase = (const char*)data4;
  const char* Bbase = (const char*)w4;

  // stage K-tile kt into buffer half `b` (8 global_load_lds per wave)
#define STAGE(b, kt)                                                                        \
  {                                                                                         \
    _Pragma("unroll")                                                                       \
    for (int u = 0; u < 4; ++u) {                                                           \
      int row = wid * 32 + u * 8 + srow;                                                    \
      int sw = ((slot ^ (row & 7)) * 16);                                                   \
      const char* ga = Abase + (size_t)(m0 + row) * 1024 + (kt) * 128 + sw;                 \
      const char* gb = Bbase + (size_t)(n0 + row) * 1024 + (kt) * 128 + sw;                 \
      int lbo = __builtin_amdgcn_readfirstlane((b) * 16384 + wid * 4096 + u * 1024);        \
      __builtin_amdgcn_global_load_lds((const __attribute__((address_space(1))) void*)ga,   \
                                       (__attribute__((address_space(3))) void*)((char*)As + lbo), 16, 0, 0); \
      __builtin_amdgcn_global_load_lds((const __attribute__((address_space(1))) void*)gb,   \
                                       (__attribute__((address_space(3))) void*)((char*)Bs + lbo), 16, 0, 0); \
    }                                                                                       \
  }

  STAGE(0, 0);   // prologue: 8 loads in flight

  for (int kt = 0; kt < 8; ++kt) {
    int cur = kt & 1;
    if (kt < 7) {
      STAGE(cur ^ 1, kt + 1);                              // 16 in flight
      asm volatile("s_waitcnt vmcnt(8)" ::: "memory");     // wait tile kt only
    } else {
      asm volatile("s_waitcnt vmcnt(0)" ::: "memory");
    }
    __builtin_amdgcn_s_barrier();                          // all waves' tile-kt writes done
    int g8 = lane >> 4;
    int bb = cur * 16384;
#pragma unroll
    for (int kk = 0; kk < 2; ++kk) {
      short8v af[4], bfr[4];
#pragma unroll
      for (int m = 0; m < 4; ++m) {
        int r = wrr + m * 16 + (lane & 15);
        int byteoff = bb + r * 128 + (((kk * 4 + g8) ^ (r & 7)) * 16);
        af[m] = *(const short8v*)((const char*)As + byteoff);
      }
#pragma unroll
      for (int n = 0; n < 4; ++n) {
        int r = wcc + n * 16 + (lane & 15);
        int byteoff = bb + r * 128 + (((kk * 4 + g8) ^ (r & 7)) * 16);
        bfr[n] = *(const short8v*)((const char*)Bs + byteoff);
      }
#pragma unroll
      for (int m = 0; m < 4; ++m)
#pragma unroll
        for (int n = 0; n < 4; ++n)
          acc[m][n] = __builtin_amdgcn_mfma_f32_16x16x32_bf16(af[m], bfr[n], acc[m][n], 0, 0, 0);
    }
    __builtin_amdgcn_s_barrier();   // reads of buf `cur` done before it is restaged
  }
#undef STAGE

  // epilogue: tanh -> out
  int g8 = lane >> 4, lc = lane & 15;
#pragma unroll
  for (int m = 0; m < 4; ++m)
#pragma unroll
    for (int n = 0; n < 4; ++n)
#pragma unroll
      for (int q = 0; q < 4; ++q) {
        int row = m0 + wrr + m * 16 + g8 * 4 + q;
        int col = n0 + wcc + n * 16 + lc;
        float x = acc[m][n][q];
        float e2 = __expf(2.f * x);
        out[(size_t)row * 32000 + col] = (e2 - 1.f) / (e2 + 1.f);
      }
}

// ---------------- kernel 6: target fill (1.0f) + fused event scatter ----------------
__global__ __launch_bounds__(256) void k_fill(const int* __restrict__ ev,
                                              float* __restrict__ target) {
  int b = blockIdx.x;
  float4* row4 = (float4*)(target + (size_t)b * 32000);
  float4 one = {1.f, 1.f, 1.f, 1.f};
#pragma unroll 4
  for (int j = threadIdx.x; j < 8000; j += 256) row4[j] = one;
  __syncthreads();   // order zero-writes after fills (workgroup scope)
  if (threadIdx.x < 50) {
    int et = ev[b * 50 + threadIdx.x];
    if (et > 0) ((float*)row4)[et - 1] = 0.f;
  }
}

extern "C" void kernel_launch(void* const* d_in, const int* in_sizes, int n_in,
                              void* d_out, int out_size, void* d_ws, size_t ws_size,
                              hipStream_t stream) {
  const float* enc = (const float*)d_in[0];
  const int* ev = (const int*)d_in[1];
  // d_in[2] = user_type: unused by the reference
  const float* W1 = (const float*)d_in[3];
  const float* W2 = (const float*)d_in[4];
  const float* W3 = (const float*)d_in[5];
  const float* W4 = (const float*)d_in[6];
  const float* pa = (const float*)d_in[7];
  const float* pb = (const float*)d_in[8];
  const float* pc = (const float*)d_in[9];
  const float* pd = (const float*)d_in[10];

  float* out = (float*)d_out;
  float* target = out + (size_t)B_SZ * T_SZ;

  char* ws = (char*)d_ws;
  unsigned short* data4 = (unsigned short*)(ws + (1 << 20));  // 2 MB @ 1M
  float* G = (float*)(ws + 3 * (1 << 20));                    // 256 KB @ 3M
  unsigned short* w4 = (unsigned short*)(ws + 4 * (1 << 20)); // 31.25 MB @ 4M
  float* Gp = (float*)(ws + 36 * (size_t)(1 << 20));          // 12.8 MB @ 36M

  k_cast<<<8000, 256, 0, stream>>>(W1, W2, W3, W4, w4);
  k_gram<<<200, 256, 0, stream>>>(w4, Gp);
  k_greduce<<<64, 256, 0, stream>>>(Gp, G);
  k_norm<<<128, 256, 0, stream>>>(enc, G, pa, pb, pc, pd, data4);
  k_gemm<<<4000, 256, 0, stream>>>(data4, w4, out);
  k_fill<<<2048, 256, 0, stream>>>(ev, target);
}